// Round 4
// baseline (8522.414 us; speedup 1.0000x reference)
//
#include <hip/hip_runtime.h>
#include <stdint.h>
#include <stddef.h>

#define S_LEN 512
#define BATCH 256
#define NIN   64
#define HD    512
#define G4    2048   // 4*H

typedef _Float16 f16;
typedef _Float16 f16x8 __attribute__((ext_vector_type(8)));
typedef float    f32x4 __attribute__((ext_vector_type(4)));
typedef uint32_t u32x4 __attribute__((ext_vector_type(4)));

// ============================ prep kernels ============================
__global__ void k_f32_to_f16(const float* __restrict__ src, f16* __restrict__ dst, int n) {
  int i = blockIdx.x * 256 + threadIdx.x;
  if (i < n) dst[i] = (f16)src[i];
}

// x [B,S,I] fp32 -> xin [(s*256+b)*64+i] fp16  (seq-major rows for the proj GEMM)
__global__ void k_x_transpose(const float* __restrict__ x, f16* __restrict__ xin) {
  int idx = blockIdx.x * 256 + threadIdx.x;
  int i  = idx & 63;
  int sb = idx >> 6;
  int b  = sb & 255;
  int s  = sb >> 8;
  xin[idx] = (f16)x[((size_t)b * S_LEN + s) * NIN + i];
}

__global__ void k_zero_i32(uint32_t* p, int n) {
  int i = blockIdx.x * 256 + threadIdx.x;
  if (i < n) p[i] = 0u;
}

// ====================== projection GEMM ======================
// C[M,2048] = A[M,K] @ W[2048,K]^T + bias   (A,W,C fp16; accum fp32)
// 128x128 tile, BK=32, 4 waves each 64x64 (4x4 MFMA 16x16x32 tiles).
template<int K>
__global__ __launch_bounds__(256) void k_proj(const f16* __restrict__ A,
                                              const f16* __restrict__ W,
                                              const float* __restrict__ bias,
                                              f16* __restrict__ C) {
  constexpr int PITCH = 40;            // f16/row in LDS: 32 data + 8 pad
  __shared__ f16 lA[128 * PITCH];
  __shared__ f16 lB[128 * PITCH];
  const int m0 = blockIdx.x * 128;
  const int n0 = blockIdx.y * 128;
  const int tid  = threadIdx.x;
  const int lane = tid & 63;
  const int wave = tid >> 6;
  const int wm = (wave & 1) * 64;
  const int wn = (wave >> 1) * 64;
  const int ln = lane & 15;
  const int quad = lane >> 4;
  const int r  = tid >> 1;             // 0..127 (tile row staged by this thread)
  const int ce = (tid & 1) * 16;       // f16 element offset (0 or 16) = 32B half

  f32x4 acc[4][4] = {};

  for (int kb = 0; kb < K; kb += 32) {
    const f16* ga = A + (size_t)(m0 + r) * K + kb + ce;
    const f16* gb = W + (size_t)(n0 + r) * K + kb + ce;
    u32x4 a0 = *(const u32x4*)ga;
    u32x4 a1 = *(const u32x4*)(ga + 8);
    u32x4 b0 = *(const u32x4*)gb;
    u32x4 b1 = *(const u32x4*)(gb + 8);
    __syncthreads();                   // prior compute done before overwrite
    *(u32x4*)&lA[r * PITCH + ce]     = a0;
    *(u32x4*)&lA[r * PITCH + ce + 8] = a1;
    *(u32x4*)&lB[r * PITCH + ce]     = b0;
    *(u32x4*)&lB[r * PITCH + ce + 8] = b1;
    __syncthreads();
    f16x8 af[4], bf[4];
#pragma unroll
    for (int i = 0; i < 4; i++) {
      af[i] = *(const f16x8*)&lA[(wm + i * 16 + ln) * PITCH + quad * 8];
      bf[i] = *(const f16x8*)&lB[(wn + i * 16 + ln) * PITCH + quad * 8];
    }
#pragma unroll
    for (int mi = 0; mi < 4; mi++)
#pragma unroll
      for (int ni = 0; ni < 4; ni++)
        acc[mi][ni] = __builtin_amdgcn_mfma_f32_16x16x32_f16(af[mi], bf[ni], acc[mi][ni], 0, 0, 0);
  }

  // epilogue: + bias, store fp16.  (layout verified end-to-end in R2/R3)
#pragma unroll
  for (int ni = 0; ni < 4; ni++) {
    const int n = n0 + wn + ni * 16 + ln;
    const float bv = bias[n];
#pragma unroll
    for (int mi = 0; mi < 4; mi++) {
#pragma unroll
      for (int rr = 0; rr < 4; rr++) {
        const int m = m0 + wm + mi * 16 + quad * 4 + rr;
        C[(size_t)m * G4 + n] = (f16)(acc[mi][ni][rr] + bv);
      }
    }
  }
}

// ====================== persistent recurrent kernel (one chunk of T steps) ======================
// Grid: 256 WGs x 512 threads.  blockIdx = gi*16 + bi  (bi-group WGs share blockIdx%8 -> same XCD).
// WG (bi,gi): batch rows [bi*16,+16), hidden cols [gi*32,+32) across 4 gates (128 gate-rows).
// Wave w (0..7): gate w>>1, sub-tile w&1 -> 16 gate-cols; weights pinned in 64 VGPRs via asm launder.
//
// Sync: TAG-IN-WORD. h element at global step t is a u32: (t & 0xffff)<<16 | fp16bits, in a 4-deep
// ring ring[(t%4)][256][512].  One relaxed agent atomic store IS the publish; consumers poll the
// data words directly (per-thread, no counters, no barriers before staging, no fences anywhere).
// Lag between WGs of a group is <=1 step, so ring depth 4 can never overwrite live data.
// A plain-fp16 copy (hclean) feeds the next layer's proj GEMM via kernel-boundary coherence.
__global__ __launch_bounds__(512, 2) void k_recur(
    const f16* __restrict__ Whh,      // [2048, 512] fp16
    const f16* __restrict__ xw,       // [T*256, 2048] fp16 (bias included)
    uint32_t* __restrict__ ring,      // [4, 256, 512] tagged u32
    f16* __restrict__ hclean,         // [T,256,512] (cleanAll) or [256,512] (last step only)
    float* __restrict__ cbuf,         // [256, 512] fp32 (carried across chunks)
    int t0, int T, int cleanAll) {
  const int tid  = threadIdx.x;
  const int lane = tid & 63;
  const int wave = tid >> 6;        // 0..7
  const int gi = blockIdx.x >> 4;
  const int bi = blockIdx.x & 15;
  const int ln = lane & 15;
  const int quad = lane >> 4;

  __shared__ f16  lh[16 * 520];     // h-tile [16 rows][512] pitch 520
  __shared__ float lgate[16 * 132]; // gates [16 b][128] fp32, pitch 132

  // --- W_hh fragments -> registers, pinned (asm makes them opaque: cannot be re-materialized) ---
  const int grow = (wave >> 1) * HD + gi * 32 + (wave & 1) * 16 + ln;  // row in [2048,512]
  f16x8 wf[16];
#pragma unroll
  for (int ks = 0; ks < 16; ks++) {
    u32x4 t = *(const u32x4*)(Whh + (size_t)grow * HD + ks * 32 + quad * 8);
    asm volatile("" : "+v"(t));
    wf[ks] = __builtin_bit_cast(f16x8, t);
  }

  // --- per-thread state: one (b,hl): b=tid>>5 (0..15), hl=tid&31 ---
  const int b_  = tid >> 5;
  const int hl_ = tid & 31;
  float cv = 0.f;
  if (t0 != 0) cv = cbuf[(size_t)(bi * 16 + b_) * HD + gi * 32 + hl_];

  unsigned short* lh16 = (unsigned short*)lh;

  for (int tt = 0; tt < T; tt++) {
    const int t = t0 + tt;

    // xw prefetch (independent of h) — issue first
    const f16* xwp = xw + (size_t)(tt * 256 + bi * 16 + b_) * G4 + gi * 32 + hl_;
    float xg0 = (float)xwp[0];
    float xg1 = (float)xwp[512];
    float xg2 = (float)xwp[1024];
    float xg3 = (float)xwp[1536];

    // poll + stage: 16 tagged words per thread (rows 0..15, col = tid)
    const uint32_t* hin = ring + (size_t)(t & 3) * (BATCH * HD) + (size_t)(bi * 16) * HD;
    const uint32_t expTag = (uint32_t)(t & 0xffff);
    uint32_t v[16];
#pragma unroll
    for (int i = 0; i < 16; i++)
      v[i] = __hip_atomic_load(hin + i * 512 + tid, __ATOMIC_RELAXED, __HIP_MEMORY_SCOPE_AGENT);
#pragma unroll
    for (int i = 0; i < 16; i++) {
      while ((v[i] >> 16) != expTag) {
        __builtin_amdgcn_s_sleep(1);
        v[i] = __hip_atomic_load(hin + i * 512 + tid, __ATOMIC_RELAXED, __HIP_MEMORY_SCOPE_AGENT);
      }
      lh16[i * 520 + tid] = (unsigned short)(v[i] & 0xffffu);
    }
    __syncthreads();   // staging complete

    // h @ Whh^T : each wave 16 gate-cols
    f32x4 acc = {0.f, 0.f, 0.f, 0.f};
#pragma unroll
    for (int ks = 0; ks < 16; ks++) {
      f16x8 af = *(const f16x8*)&lh[ln * 520 + ks * 32 + quad * 8];
      acc = __builtin_amdgcn_mfma_f32_16x16x32_f16(af, wf[ks], acc, 0, 0, 0);
    }
    const int gcol = (wave >> 1) * 32 + (wave & 1) * 16 + ln;
#pragma unroll
    for (int rr = 0; rr < 4; rr++)
      lgate[(quad * 4 + rr) * 132 + gcol] = acc[rr];
    __syncthreads();   // gates complete

    // elementwise LSTM update: one (b,hl) per thread
    {
      float gi_ = lgate[b_ * 132 + 0  + hl_] + xg0;
      float gf_ = lgate[b_ * 132 + 32 + hl_] + xg1;
      float gg_ = lgate[b_ * 132 + 64 + hl_] + xg2;
      float go_ = lgate[b_ * 132 + 96 + hl_] + xg3;
      const float ig = 1.f / (1.f + expf(-gi_));
      const float fg = 1.f / (1.f + expf(-gf_));
      const float gg = gg_ > 0.f ? gg_ : expm1f(gg_);
      const float og = 1.f / (1.f + expf(-go_));
      cv = fg * cv + ig * gg;
      const float hv = og * (cv > 0.f ? cv : expm1f(cv));
      f16 hv16 = (f16)hv;
      unsigned short us;
      __builtin_memcpy(&us, &hv16, 2);
      // publish tagged word (single 32b atomic = data + flag)
      const uint32_t word = ((uint32_t)((t + 1) & 0xffff) << 16) | (uint32_t)us;
      uint32_t* rout = ring + (size_t)((t + 1) & 3) * (BATCH * HD)
                     + (size_t)(bi * 16 + b_) * HD + gi * 32 + hl_;
      __hip_atomic_store(rout, word, __ATOMIC_RELAXED, __HIP_MEMORY_SCOPE_AGENT);
      // clean copy for next layer's proj (plain store; kernel-boundary coherence)
      if (cleanAll)
        hclean[(size_t)(tt * 256 + bi * 16 + b_) * HD + gi * 32 + hl_] = hv16;
      else if (tt == T - 1)
        hclean[(size_t)(bi * 16 + b_) * HD + gi * 32 + hl_] = hv16;
    }
    // no third barrier: next iter's lh writes only happen after all waves passed the
    // post-gate __syncthreads (which follows every wave's lh reads)
  }

  // save c state for next chunk
  cbuf[(size_t)(bi * 16 + b_) * HD + gi * 32 + hl_] = cv;
}

// ====================== final FC: y[b] = h_last[b,:] . fc_w + fc_b ======================
__global__ __launch_bounds__(64) void k_fc(const f16* __restrict__ hlast,
                                           const float* __restrict__ fcw,
                                           const float* __restrict__ fcb,
                                           float* __restrict__ out) {
  const int b = blockIdx.x, lane = threadIdx.x;
  const f16* hp = hlast + (size_t)b * HD + lane * 8;
  float s = 0.f;
#pragma unroll
  for (int j = 0; j < 8; j++) s += (float)hp[j] * fcw[lane * 8 + j];
  for (int off = 32; off; off >>= 1) s += __shfl_down(s, off);
  if (lane == 0) out[b] = s + fcb[0];
}

// ============================ host ============================
extern "C" void kernel_launch(void* const* d_in, const int* in_sizes, int n_in,
                              void* d_out, int out_size, void* d_ws, size_t ws_size,
                              hipStream_t stream) {
  (void)in_sizes; (void)n_in; (void)out_size;
  const float* x      = (const float*)d_in[0];
  const float* wih[3] = {(const float*)d_in[1], (const float*)d_in[4], (const float*)d_in[7]};
  const float* whh[3] = {(const float*)d_in[2], (const float*)d_in[5], (const float*)d_in[8]};
  const float* bia[3] = {(const float*)d_in[3], (const float*)d_in[6], (const float*)d_in[9]};
  const float* fcw = (const float*)d_in[10];
  const float* fcb = (const float*)d_in[11];
  float* out = (float*)d_out;

  char* ws = (char*)d_ws;
  size_t off = 0;
  auto alloc = [&](size_t bytes) -> char* {
    off = (off + 255) & ~(size_t)255;
    char* p = ws + off;
    off += bytes;
    return p;
  };

  // ---- fixed allocations (~34 MB) ----
  f16* xin = (f16*)alloc((size_t)S_LEN * BATCH * NIN * 2);
  f16* wih16[3];
  wih16[0] = (f16*)alloc((size_t)G4 * NIN * 2);
  wih16[1] = (f16*)alloc((size_t)G4 * HD * 2);
  wih16[2] = (f16*)alloc((size_t)G4 * HD * 2);
  f16* whh16[3];
  for (int l = 0; l < 3; l++) whh16[l] = (f16*)alloc((size_t)G4 * HD * 2);
  float* cbuf[3];
  for (int l = 0; l < 3; l++) cbuf[l] = (float*)alloc((size_t)BATCH * HD * 4);
  uint32_t* ring[3];
  for (int l = 0; l < 3; l++) ring[l] = (uint32_t*)alloc((size_t)4 * BATCH * HD * 4);
  f16* hclean2 = (f16*)alloc((size_t)BATCH * HD * 2);

  // ---- adaptive chunk length T ----
  int T = 64;
  while (T > 4) {
    size_t need = off + 8 * 256
                + 2 * ((size_t)T * BATCH * HD * 2 + 256)   // hclean0, hclean1
                + (size_t)T * BATCH * G4 * 2;              // xw
    if (need <= ws_size) break;
    T >>= 1;
  }
  f16* hclean01[2];
  hclean01[0] = (f16*)alloc((size_t)T * BATCH * HD * 2);
  hclean01[1] = (f16*)alloc((size_t)T * BATCH * HD * 2);
  f16* xw = (f16*)alloc((size_t)T * BATCH * G4 * 2);

  // ---- prep ----
  {
    int n = S_LEN * BATCH * NIN;
    k_x_transpose<<<dim3(n / 256), dim3(256), 0, stream>>>(x, xin);
  }
  k_f32_to_f16<<<dim3((G4 * NIN + 255) / 256), dim3(256), 0, stream>>>(wih[0], wih16[0], G4 * NIN);
  k_f32_to_f16<<<dim3((G4 * HD + 255) / 256), dim3(256), 0, stream>>>(wih[1], wih16[1], G4 * HD);
  k_f32_to_f16<<<dim3((G4 * HD + 255) / 256), dim3(256), 0, stream>>>(wih[2], wih16[2], G4 * HD);
  for (int l = 0; l < 3; l++)
    k_f32_to_f16<<<dim3((G4 * HD + 255) / 256), dim3(256), 0, stream>>>(whh[l], whh16[l], G4 * HD);
  // zero ring slot 0 of each layer: tag 0 | h 0  (== h_{-1} = 0 with expected tag 0)
  for (int l = 0; l < 3; l++)
    k_zero_i32<<<dim3(BATCH * HD / 256), dim3(256), 0, stream>>>(ring[l], BATCH * HD);

  // ---- chunk-interleaved layers ----
  for (int t0 = 0; t0 < S_LEN; t0 += T) {
    for (int l = 0; l < 3; l++) {
      dim3 pg(T * BATCH / 128, G4 / 128);
      if (l == 0) {
        const f16* Achunk = xin + (size_t)t0 * BATCH * NIN;
        k_proj<NIN><<<pg, dim3(256), 0, stream>>>(Achunk, wih16[0], bia[0], xw);
      } else {
        k_proj<HD><<<pg, dim3(256), 0, stream>>>(hclean01[l - 1], wih16[l], bia[l], xw);
      }
      f16* hc = (l == 2) ? hclean2 : hclean01[l];
      k_recur<<<dim3(256), dim3(512), 0, stream>>>(whh16[l], xw, ring[l], hc, cbuf[l],
                                                   t0, T, l != 2);
    }
  }

  // ---- final FC ----
  k_fc<<<dim3(BATCH), dim3(64), 0, stream>>>(hclean2, fcw, fcb, out);
}

// Round 5
// 7443.156 us; speedup vs baseline: 1.1450x; 1.1450x over previous
//
#include <hip/hip_runtime.h>
#include <stdint.h>
#include <stddef.h>

#define S_LEN 512
#define BATCH 256
#define NIN   64
#define HD    512
#define G4    2048   // 4*H

typedef _Float16 f16;
typedef _Float16 f16x8 __attribute__((ext_vector_type(8)));
typedef float    f32x4 __attribute__((ext_vector_type(4)));
typedef uint32_t u32x4 __attribute__((ext_vector_type(4)));

// ============================ prep kernels ============================
__global__ void k_f32_to_f16(const float* __restrict__ src, f16* __restrict__ dst, int n) {
  int i = blockIdx.x * 256 + threadIdx.x;
  if (i < n) dst[i] = (f16)src[i];
}

// x [B,S,I] fp32 -> xin [(s*256+b)*64+i] fp16  (seq-major rows for the proj GEMM)
__global__ void k_x_transpose(const float* __restrict__ x, f16* __restrict__ xin) {
  int idx = blockIdx.x * 256 + threadIdx.x;
  int i  = idx & 63;
  int sb = idx >> 6;
  int b  = sb & 255;
  int s  = sb >> 8;
  xin[idx] = (f16)x[((size_t)b * S_LEN + s) * NIN + i];
}

__global__ void k_zero_i32(uint32_t* p, int n) {
  int i = blockIdx.x * 256 + threadIdx.x;
  if (i < n) p[i] = 0u;
}

// ====================== projection GEMM ======================
// C[M,2048] = A[M,K] @ W[2048,K]^T + bias   (A,W,C fp16; accum fp32)
// 128x128 tile, BK=32, 4 waves each 64x64 (4x4 MFMA 16x16x32 tiles).
template<int K>
__global__ __launch_bounds__(256) void k_proj(const f16* __restrict__ A,
                                              const f16* __restrict__ W,
                                              const float* __restrict__ bias,
                                              f16* __restrict__ C) {
  constexpr int PITCH = 40;            // f16/row in LDS: 32 data + 8 pad
  __shared__ f16 lA[128 * PITCH];
  __shared__ f16 lB[128 * PITCH];
  const int m0 = blockIdx.x * 128;
  const int n0 = blockIdx.y * 128;
  const int tid  = threadIdx.x;
  const int lane = tid & 63;
  const int wave = tid >> 6;
  const int wm = (wave & 1) * 64;
  const int wn = (wave >> 1) * 64;
  const int ln = lane & 15;
  const int quad = lane >> 4;
  const int r  = tid >> 1;             // 0..127 (tile row staged by this thread)
  const int ce = (tid & 1) * 16;       // f16 element offset (0 or 16) = 32B half

  f32x4 acc[4][4] = {};

  for (int kb = 0; kb < K; kb += 32) {
    const f16* ga = A + (size_t)(m0 + r) * K + kb + ce;
    const f16* gb = W + (size_t)(n0 + r) * K + kb + ce;
    u32x4 a0 = *(const u32x4*)ga;
    u32x4 a1 = *(const u32x4*)(ga + 8);
    u32x4 b0 = *(const u32x4*)gb;
    u32x4 b1 = *(const u32x4*)(gb + 8);
    __syncthreads();                   // prior compute done before overwrite
    *(u32x4*)&lA[r * PITCH + ce]     = a0;
    *(u32x4*)&lA[r * PITCH + ce + 8] = a1;
    *(u32x4*)&lB[r * PITCH + ce]     = b0;
    *(u32x4*)&lB[r * PITCH + ce + 8] = b1;
    __syncthreads();
    f16x8 af[4], bf[4];
#pragma unroll
    for (int i = 0; i < 4; i++) {
      af[i] = *(const f16x8*)&lA[(wm + i * 16 + ln) * PITCH + quad * 8];
      bf[i] = *(const f16x8*)&lB[(wn + i * 16 + ln) * PITCH + quad * 8];
    }
#pragma unroll
    for (int mi = 0; mi < 4; mi++)
#pragma unroll
      for (int ni = 0; ni < 4; ni++)
        acc[mi][ni] = __builtin_amdgcn_mfma_f32_16x16x32_f16(af[mi], bf[ni], acc[mi][ni], 0, 0, 0);
  }

  // epilogue: + bias, store fp16.  (layout verified end-to-end in R2/R3)
#pragma unroll
  for (int ni = 0; ni < 4; ni++) {
    const int n = n0 + wn + ni * 16 + ln;
    const float bv = bias[n];
#pragma unroll
    for (int mi = 0; mi < 4; mi++) {
#pragma unroll
      for (int rr = 0; rr < 4; rr++) {
        const int m = m0 + wm + mi * 16 + quad * 4 + rr;
        C[(size_t)m * G4 + n] = (f16)(acc[mi][ni][rr] + bv);
      }
    }
  }
}

// ====================== persistent recurrent kernel (one chunk of T steps) ======================
// Grid: 256 WGs x 512 threads.  blockIdx = gi*16 + bi  (bi-group WGs share blockIdx%8 -> same XCD).
// WG (bi,gi): batch rows [bi*16,+16), hidden cols [gi*32,+32) across 4 gates (128 gate-rows).
// Wave w (0..7): gate w>>1, sub-tile w&1 -> 16 gate-cols; weights live in the unified VGPR/AGPR file.
//
// Sync: TAG-IN-WORD, PARALLEL SWEEP POLL. h element at global step t is a u32:
// (t&0xffff)<<16 | fp16bits, in a 4-deep ring.  One relaxed agent atomic store IS the publish.
// Consumers poll u64 (2 tagged elements) and, on a failed sweep, re-issue ALL stale loads
// back-to-back -> one fabric latency per sweep instead of one per word (R4 bug: sequential
// per-word resolution cost 16 round trips = 4.8us/step).
__global__ __launch_bounds__(512, 2) void k_recur(
    const f16* __restrict__ Whh,      // [2048, 512] fp16
    const f16* __restrict__ xw,       // [T*256, 2048] fp16 (bias included)
    uint32_t* __restrict__ ring,      // [4, 256, 512] tagged u32
    f16* __restrict__ hclean,         // [T,256,512] (cleanAll) or [256,512] (last step only)
    float* __restrict__ cbuf,         // [256, 512] fp32 (carried across chunks)
    int t0, int T, int cleanAll) {
  const int tid  = threadIdx.x;
  const int lane = tid & 63;
  const int wave = tid >> 6;        // 0..7
  const int gi = blockIdx.x >> 4;
  const int bi = blockIdx.x & 15;
  const int ln = lane & 15;
  const int quad = lane >> 4;

  __shared__ f16  lh[16 * 520];     // h-tile [16 rows][512] pitch 520
  __shared__ float lgate[16 * 132]; // gates [16 b][128] fp32, pitch 132

  // --- W_hh fragments -> registers (once); asm launder prevents rematerialization ---
  const int grow = (wave >> 1) * HD + gi * 32 + (wave & 1) * 16 + ln;  // row in [2048,512]
  f16x8 wf[16];
#pragma unroll
  for (int ks = 0; ks < 16; ks++) {
    u32x4 t = *(const u32x4*)(Whh + (size_t)grow * HD + ks * 32 + quad * 8);
    asm volatile("" : "+v"(t));
    wf[ks] = __builtin_bit_cast(f16x8, t);
  }

  // --- per-thread state: one (b,hl): b=tid>>5 (0..15), hl=tid&31 ---
  const int b_  = tid >> 5;
  const int hl_ = tid & 31;
  float cv = 0.f;
  if (t0 != 0) cv = cbuf[(size_t)(bi * 16 + b_) * HD + gi * 32 + hl_];

  unsigned short* lh16 = (unsigned short*)lh;
  const int half = tid >> 8;        // 0..1 : which 8-row half this thread stages
  const int ti   = tid & 255;       // col-pair index (u64 = 2 adjacent u32 elements)

  for (int tt = 0; tt < T; tt++) {
    const int t = t0 + tt;

    // ---- poll + stage: 8 tagged u64 per thread (rows half*8+j, col pair ti) ----
    const uint64_t* hin64 = (const uint64_t*)(ring + (size_t)(t & 3) * (BATCH * HD)
                                              + (size_t)(bi * 16) * HD);
    const uint32_t expTag = (uint32_t)(t & 0xffff);
    const uint64_t exp2  = ((uint64_t)expTag << 48) | ((uint64_t)expTag << 16);
    const uint64_t mask2 = 0xffff0000ffff0000ull;
    uint64_t v[8];
#pragma unroll
    for (int j = 0; j < 8; j++)
      v[j] = __hip_atomic_load(hin64 + (size_t)(half * 8 + j) * 256 + ti,
                               __ATOMIC_RELAXED, __HIP_MEMORY_SCOPE_AGENT);

    // xw prefetch (independent of h), issued behind the ring loads
    const f16* xwp = xw + (size_t)(tt * 256 + bi * 16 + b_) * G4 + gi * 32 + hl_;
    float xg0 = (float)xwp[0];
    float xg1 = (float)xwp[512];
    float xg2 = (float)xwp[1024];
    float xg3 = (float)xwp[1536];

    // parallel sweep: re-issue ALL stale loads per sweep (one fabric latency per sweep)
    for (;;) {
      bool all = true;
#pragma unroll
      for (int j = 0; j < 8; j++)
        if ((v[j] & mask2) != exp2) all = false;
      if (all) break;
      __builtin_amdgcn_s_sleep(1);
#pragma unroll
      for (int j = 0; j < 8; j++)
        if ((v[j] & mask2) != exp2)
          v[j] = __hip_atomic_load(hin64 + (size_t)(half * 8 + j) * 256 + ti,
                                   __ATOMIC_RELAXED, __HIP_MEMORY_SCOPE_AGENT);
    }
#pragma unroll
    for (int j = 0; j < 8; j++) {
      const int r = half * 8 + j;
      const uint32_t packed = (uint32_t)(v[j] & 0xffffu)
                            | (((uint32_t)(v[j] >> 32) & 0xffffu) << 16);
      *(uint32_t*)&lh16[r * 520 + 2 * ti] = packed;
    }
    __syncthreads();   // staging complete

    // h @ Whh^T : each wave 16 gate-cols
    f32x4 acc = {0.f, 0.f, 0.f, 0.f};
#pragma unroll
    for (int ks = 0; ks < 16; ks++) {
      f16x8 af = *(const f16x8*)&lh[ln * 520 + ks * 32 + quad * 8];
      acc = __builtin_amdgcn_mfma_f32_16x16x32_f16(af, wf[ks], acc, 0, 0, 0);
    }
    const int gcol = (wave >> 1) * 32 + (wave & 1) * 16 + ln;
#pragma unroll
    for (int rr = 0; rr < 4; rr++)
      lgate[(quad * 4 + rr) * 132 + gcol] = acc[rr];
    __syncthreads();   // gates complete

    // elementwise LSTM update: one (b,hl) per thread
    {
      float gi_ = lgate[b_ * 132 + 0  + hl_] + xg0;
      float gf_ = lgate[b_ * 132 + 32 + hl_] + xg1;
      float gg_ = lgate[b_ * 132 + 64 + hl_] + xg2;
      float go_ = lgate[b_ * 132 + 96 + hl_] + xg3;
      const float ig = 1.f / (1.f + expf(-gi_));
      const float fg = 1.f / (1.f + expf(-gf_));
      const float gg = gg_ > 0.f ? gg_ : expm1f(gg_);
      const float og = 1.f / (1.f + expf(-go_));
      cv = fg * cv + ig * gg;
      const float hv = og * (cv > 0.f ? cv : expm1f(cv));
      f16 hv16 = (f16)hv;
      unsigned short us;
      __builtin_memcpy(&us, &hv16, 2);
      // publish tagged word (single 32b atomic = data + flag)
      const uint32_t word = ((uint32_t)((t + 1) & 0xffff) << 16) | (uint32_t)us;
      uint32_t* rout = ring + (size_t)((t + 1) & 3) * (BATCH * HD)
                     + (size_t)(bi * 16 + b_) * HD + gi * 32 + hl_;
      __hip_atomic_store(rout, word, __ATOMIC_RELAXED, __HIP_MEMORY_SCOPE_AGENT);
      // clean copy for next layer's proj (plain store; kernel-boundary coherence)
      if (cleanAll)
        hclean[(size_t)(tt * 256 + bi * 16 + b_) * HD + gi * 32 + hl_] = hv16;
      else if (tt == T - 1)
        hclean[(size_t)(bi * 16 + b_) * HD + gi * 32 + hl_] = hv16;
    }
    // no third barrier needed: next iter's lh writes happen only after the post-gate
    // __syncthreads, which follows every wave's lh reads
  }

  // save c state for next chunk
  cbuf[(size_t)(bi * 16 + b_) * HD + gi * 32 + hl_] = cv;
}

// ====================== final FC: y[b] = h_last[b,:] . fc_w + fc_b ======================
__global__ __launch_bounds__(64) void k_fc(const f16* __restrict__ hlast,
                                           const float* __restrict__ fcw,
                                           const float* __restrict__ fcb,
                                           float* __restrict__ out) {
  const int b = blockIdx.x, lane = threadIdx.x;
  const f16* hp = hlast + (size_t)b * HD + lane * 8;
  float s = 0.f;
#pragma unroll
  for (int j = 0; j < 8; j++) s += (float)hp[j] * fcw[lane * 8 + j];
  for (int off = 32; off; off >>= 1) s += __shfl_down(s, off);
  if (lane == 0) out[b] = s + fcb[0];
}

// ============================ host ============================
extern "C" void kernel_launch(void* const* d_in, const int* in_sizes, int n_in,
                              void* d_out, int out_size, void* d_ws, size_t ws_size,
                              hipStream_t stream) {
  (void)in_sizes; (void)n_in; (void)out_size;
  const float* x      = (const float*)d_in[0];
  const float* wih[3] = {(const float*)d_in[1], (const float*)d_in[4], (const float*)d_in[7]};
  const float* whh[3] = {(const float*)d_in[2], (const float*)d_in[5], (const float*)d_in[8]};
  const float* bia[3] = {(const float*)d_in[3], (const float*)d_in[6], (const float*)d_in[9]};
  const float* fcw = (const float*)d_in[10];
  const float* fcb = (const float*)d_in[11];
  float* out = (float*)d_out;

  char* ws = (char*)d_ws;
  size_t off = 0;
  auto alloc = [&](size_t bytes) -> char* {
    off = (off + 255) & ~(size_t)255;
    char* p = ws + off;
    off += bytes;
    return p;
  };

  // ---- fixed allocations (~34 MB) ----
  f16* xin = (f16*)alloc((size_t)S_LEN * BATCH * NIN * 2);
  f16* wih16[3];
  wih16[0] = (f16*)alloc((size_t)G4 * NIN * 2);
  wih16[1] = (f16*)alloc((size_t)G4 * HD * 2);
  wih16[2] = (f16*)alloc((size_t)G4 * HD * 2);
  f16* whh16[3];
  for (int l = 0; l < 3; l++) whh16[l] = (f16*)alloc((size_t)G4 * HD * 2);
  float* cbuf[3];
  for (int l = 0; l < 3; l++) cbuf[l] = (float*)alloc((size_t)BATCH * HD * 4);
  uint32_t* ring[3];
  for (int l = 0; l < 3; l++) ring[l] = (uint32_t*)alloc((size_t)4 * BATCH * HD * 4);
  f16* hclean2 = (f16*)alloc((size_t)BATCH * HD * 2);

  // ---- adaptive chunk length T ----
  int T = 64;
  while (T > 4) {
    size_t need = off + 8 * 256
                + 2 * ((size_t)T * BATCH * HD * 2 + 256)   // hclean0, hclean1
                + (size_t)T * BATCH * G4 * 2;              // xw
    if (need <= ws_size) break;
    T >>= 1;
  }
  f16* hclean01[2];
  hclean01[0] = (f16*)alloc((size_t)T * BATCH * HD * 2);
  hclean01[1] = (f16*)alloc((size_t)T * BATCH * HD * 2);
  f16* xw = (f16*)alloc((size_t)T * BATCH * G4 * 2);

  // ---- prep ----
  {
    int n = S_LEN * BATCH * NIN;
    k_x_transpose<<<dim3(n / 256), dim3(256), 0, stream>>>(x, xin);
  }
  k_f32_to_f16<<<dim3((G4 * NIN + 255) / 256), dim3(256), 0, stream>>>(wih[0], wih16[0], G4 * NIN);
  k_f32_to_f16<<<dim3((G4 * HD + 255) / 256), dim3(256), 0, stream>>>(wih[1], wih16[1], G4 * HD);
  k_f32_to_f16<<<dim3((G4 * HD + 255) / 256), dim3(256), 0, stream>>>(wih[2], wih16[2], G4 * HD);
  for (int l = 0; l < 3; l++)
    k_f32_to_f16<<<dim3((G4 * HD + 255) / 256), dim3(256), 0, stream>>>(whh[l], whh16[l], G4 * HD);
  // zero ring slot 0 of each layer: tag 0 | h 0  (== h_{-1} = 0 with expected tag 0)
  for (int l = 0; l < 3; l++)
    k_zero_i32<<<dim3(BATCH * HD / 256), dim3(256), 0, stream>>>(ring[l], BATCH * HD);

  // ---- chunk-interleaved layers ----
  for (int t0 = 0; t0 < S_LEN; t0 += T) {
    for (int l = 0; l < 3; l++) {
      dim3 pg(T * BATCH / 128, G4 / 128);
      if (l == 0) {
        const f16* Achunk = xin + (size_t)t0 * BATCH * NIN;
        k_proj<NIN><<<pg, dim3(256), 0, stream>>>(Achunk, wih16[0], bia[0], xw);
      } else {
        k_proj<HD><<<pg, dim3(256), 0, stream>>>(hclean01[l - 1], wih16[l], bia[l], xw);
      }
      f16* hc = (l == 2) ? hclean2 : hclean01[l];
      k_recur<<<dim3(256), dim3(512), 0, stream>>>(whh16[l], xw, ring[l], hc, cbuf[l],
                                                   t0, T, l != 2);
    }
  }

  // ---- final FC ----
  k_fc<<<dim3(BATCH), dim3(64), 0, stream>>>(hclean2, fcw, fcb, out);
}

// Round 6
// 5465.253 us; speedup vs baseline: 1.5594x; 1.3619x over previous
//
#include <hip/hip_runtime.h>
#include <stdint.h>
#include <stddef.h>

#define S_LEN 512
#define BATCH 256
#define NIN   64
#define HD    512
#define G4    2048   // 4*H

typedef _Float16 f16;
typedef _Float16 f16x8 __attribute__((ext_vector_type(8)));
typedef float    f32x4 __attribute__((ext_vector_type(4)));
typedef uint32_t u32x4 __attribute__((ext_vector_type(4)));

// ============================ prep kernels ============================
__global__ void k_f32_to_f16(const float* __restrict__ src, f16* __restrict__ dst, int n) {
  int i = blockIdx.x * 256 + threadIdx.x;
  if (i < n) dst[i] = (f16)src[i];
}

// x [B,S,I] fp32 -> xin [(s*256+b)*64+i] fp16  (seq-major rows for the proj GEMM)
__global__ void k_x_transpose(const float* __restrict__ x, f16* __restrict__ xin) {
  int idx = blockIdx.x * 256 + threadIdx.x;
  int i  = idx & 63;
  int sb = idx >> 6;
  int b  = sb & 255;
  int s  = sb >> 8;
  xin[idx] = (f16)x[((size_t)b * S_LEN + s) * NIN + i];
}

__global__ void k_zero_i32(uint32_t* p, int n) {
  int i = blockIdx.x * 256 + threadIdx.x;
  if (i < n) p[i] = 0u;
}

// ====================== projection GEMM ======================
// C[M,2048] = A[M,K] @ W[2048,K]^T + bias   (A,W,C fp16; accum fp32)
// 128x128 tile, BK=32, 4 waves each 64x64 (4x4 MFMA 16x16x32 tiles).
template<int K>
__global__ __launch_bounds__(256) void k_proj(const f16* __restrict__ A,
                                              const f16* __restrict__ W,
                                              const float* __restrict__ bias,
                                              f16* __restrict__ C) {
  constexpr int PITCH = 40;            // f16/row in LDS: 32 data + 8 pad
  __shared__ f16 lA[128 * PITCH];
  __shared__ f16 lB[128 * PITCH];
  const int m0 = blockIdx.x * 128;
  const int n0 = blockIdx.y * 128;
  const int tid  = threadIdx.x;
  const int lane = tid & 63;
  const int wave = tid >> 6;
  const int wm = (wave & 1) * 64;
  const int wn = (wave >> 1) * 64;
  const int ln = lane & 15;
  const int quad = lane >> 4;
  const int r  = tid >> 1;             // 0..127 (tile row staged by this thread)
  const int ce = (tid & 1) * 16;       // f16 element offset (0 or 16) = 32B half

  f32x4 acc[4][4] = {};

  for (int kb = 0; kb < K; kb += 32) {
    const f16* ga = A + (size_t)(m0 + r) * K + kb + ce;
    const f16* gb = W + (size_t)(n0 + r) * K + kb + ce;
    u32x4 a0 = *(const u32x4*)ga;
    u32x4 a1 = *(const u32x4*)(ga + 8);
    u32x4 b0 = *(const u32x4*)gb;
    u32x4 b1 = *(const u32x4*)(gb + 8);
    __syncthreads();                   // prior compute done before overwrite
    *(u32x4*)&lA[r * PITCH + ce]     = a0;
    *(u32x4*)&lA[r * PITCH + ce + 8] = a1;
    *(u32x4*)&lB[r * PITCH + ce]     = b0;
    *(u32x4*)&lB[r * PITCH + ce + 8] = b1;
    __syncthreads();
    f16x8 af[4], bf[4];
#pragma unroll
    for (int i = 0; i < 4; i++) {
      af[i] = *(const f16x8*)&lA[(wm + i * 16 + ln) * PITCH + quad * 8];
      bf[i] = *(const f16x8*)&lB[(wn + i * 16 + ln) * PITCH + quad * 8];
    }
#pragma unroll
    for (int mi = 0; mi < 4; mi++)
#pragma unroll
      for (int ni = 0; ni < 4; ni++)
        acc[mi][ni] = __builtin_amdgcn_mfma_f32_16x16x32_f16(af[mi], bf[ni], acc[mi][ni], 0, 0, 0);
  }

  // epilogue: + bias, store fp16.  (layout verified end-to-end in R2..R5)
#pragma unroll
  for (int ni = 0; ni < 4; ni++) {
    const int n = n0 + wn + ni * 16 + ln;
    const float bv = bias[n];
#pragma unroll
    for (int mi = 0; mi < 4; mi++) {
#pragma unroll
      for (int rr = 0; rr < 4; rr++) {
        const int m = m0 + wm + mi * 16 + quad * 4 + rr;
        C[(size_t)m * G4 + n] = (f16)(acc[mi][ni][rr] + bv);
      }
    }
  }
}

// ====================== persistent recurrent kernel (one chunk of T steps) ======================
// Grid: 256 WGs x 512 threads.  blockIdx = gi*16 + bi (bi-group WGs share blockIdx%8 -> same XCD).
// WG (bi,gi): batch rows [bi*16,+16), hidden cols [gi*32,+32) across 4 gates.
// Wave w (0..7): gate w>>1, sub-tile w&1 -> 16 gate-cols; weights pinned via asm launder.
//
// Sync (R6): PER-PRODUCER FLAGS + PLAIN DATA RING.
//  - flags[bi*16+gi] = number of completed steps (monotonic, single writer, relaxed agent store,
//    issued only after a __syncthreads that drains the producer's data-store vmcnt).
//  - Consumers poll ONLY the 16 flags of their group (one 64B line -> one MALL request per wave
//    per sweep; 128KB/sweep GPU-wide vs R5's 16MB data-word storm that caused 30-40ms livelocks).
//  - After flags pass, h data (plain f16 ring, 4-deep) is loaded ONCE via coalesced relaxed u64
//    atomic loads (MALL path, bypasses possibly-stale XCD L2). Data is stable: no producer touches
//    slot t again until t+4, and inter-WG skew is provably <=1 step.
__global__ __launch_bounds__(512, 2) void k_recur(
    const f16* __restrict__ Whh,      // [2048, 512] fp16
    const f16* __restrict__ xw,       // [T*256, 2048] fp16 (bias included)
    f16* __restrict__ ring,           // [4, 256, 512] f16
    int* __restrict__ flags,          // [256] per-(bi,gi) step counters (persist across chunks)
    f16* __restrict__ hclean,         // [T,256,512] (cleanAll) or [256,512] (last step only)
    float* __restrict__ cbuf,         // [256, 512] fp32 (carried across chunks)
    int t0, int T, int cleanAll) {
  const int tid  = threadIdx.x;
  const int lane = tid & 63;
  const int wave = tid >> 6;        // 0..7
  const int gi = blockIdx.x >> 4;
  const int bi = blockIdx.x & 15;
  const int ln = lane & 15;
  const int quad = lane >> 4;

  __shared__ f16  lh[16 * 520];     // h-tile [16 rows][512] pitch 520
  __shared__ float lgate[16 * 132]; // gates [16 b][128] fp32, pitch 132

  // --- W_hh fragments -> registers (once); asm launder prevents sinking into the loop ---
  const int grow = (wave >> 1) * HD + gi * 32 + (wave & 1) * 16 + ln;  // row in [2048,512]
  f16x8 wf[16];
#pragma unroll
  for (int ks = 0; ks < 16; ks++) {
    u32x4 t = *(const u32x4*)(Whh + (size_t)grow * HD + ks * 32 + quad * 8);
    asm volatile("" : "+v"(t));
    wf[ks] = __builtin_bit_cast(f16x8, t);
  }

  // --- per-thread state: one (b,hl): b=tid>>5 (0..15), hl=tid&31 ---
  const int b_  = tid >> 5;
  const int hl_ = tid & 31;
  float cv = 0.f;
  if (t0 != 0) cv = cbuf[(size_t)(bi * 16 + b_) * HD + gi * 32 + hl_];

  const int* fl = flags + bi * 16;              // this group's 16 flags (one cache line)
  int* myflag = flags + bi * 16 + gi;
  uint64_t* lh64 = (uint64_t*)lh;               // row pitch 130 u64 (=520 f16)

  for (int tt = 0; tt < T; tt++) {
    const int t = t0 + tt;

    // xw prefetch (independent of h) — issue first, lives across the poll
    const f16* xwp = xw + (size_t)(tt * 256 + bi * 16 + b_) * G4 + gi * 32 + hl_;
    float xg0 = (float)xwp[0];
    float xg1 = (float)xwp[512];
    float xg2 = (float)xwp[1024];
    float xg3 = (float)xwp[1536];

    // ---- poll the 16 producer flags (every wave independently; 1 line per sweep) ----
    {
      int v = __hip_atomic_load(fl + (lane & 15), __ATOMIC_RELAXED, __HIP_MEMORY_SCOPE_AGENT);
      while (!__all(v >= t)) {
        __builtin_amdgcn_s_sleep(1);
        v = __hip_atomic_load(fl + (lane & 15), __ATOMIC_RELAXED, __HIP_MEMORY_SCOPE_AGENT);
      }
    }
    asm volatile("" ::: "memory");   // keep data loads below the poll

    // ---- bulk-load h slot t (rows [bi*16,+16), 512 cols) ONCE: 4 coalesced u64/thread ----
    const uint64_t* hin64 = (const uint64_t*)(ring + (size_t)(t & 3) * (BATCH * HD)
                                              + (size_t)(bi * 16) * HD);
    uint64_t d[4];
#pragma unroll
    for (int j = 0; j < 4; j++)
      d[j] = __hip_atomic_load(hin64 + j * 512 + tid, __ATOMIC_RELAXED, __HIP_MEMORY_SCOPE_AGENT);
#pragma unroll
    for (int j = 0; j < 4; j++) {
      const int e   = j * 512 + tid;      // u64 index in 16x512 tile (128 u64/row)
      const int row = e >> 7;
      const int c8  = e & 127;
      lh64[row * 130 + c8] = d[j];
    }
    __syncthreads();   // staging complete

    // ---- h @ Whh^T : each wave 16 gate-cols ----
    f32x4 acc = {0.f, 0.f, 0.f, 0.f};
#pragma unroll
    for (int ks = 0; ks < 16; ks++) {
      f16x8 af = *(const f16x8*)&lh[ln * 520 + ks * 32 + quad * 8];
      acc = __builtin_amdgcn_mfma_f32_16x16x32_f16(af, wf[ks], acc, 0, 0, 0);
    }
    const int gcol = (wave >> 1) * 32 + (wave & 1) * 16 + ln;
#pragma unroll
    for (int rr = 0; rr < 4; rr++)
      lgate[(quad * 4 + rr) * 132 + gcol] = acc[rr];
    __syncthreads();   // gates complete

    // ---- elementwise LSTM update: one (b,hl) per thread ----
    {
      float gi_ = lgate[b_ * 132 + 0  + hl_] + xg0;
      float gf_ = lgate[b_ * 132 + 32 + hl_] + xg1;
      float gg_ = lgate[b_ * 132 + 64 + hl_] + xg2;
      float go_ = lgate[b_ * 132 + 96 + hl_] + xg3;
      const float ig = 1.f / (1.f + expf(-gi_));
      const float fg = 1.f / (1.f + expf(-gf_));
      const float gg = gg_ > 0.f ? gg_ : expm1f(gg_);
      const float og = 1.f / (1.f + expf(-go_));
      cv = fg * cv + ig * gg;
      const float hv = og * (cv > 0.f ? cv : expm1f(cv));
      f16 hv16 = (f16)hv;
      unsigned short us;
      __builtin_memcpy(&us, &hv16, 2);
      const size_t col = (size_t)(bi * 16 + b_) * HD + gi * 32 + hl_;
      __hip_atomic_store((unsigned short*)(ring + (size_t)((t + 1) & 3) * (BATCH * HD) + col),
                         us, __ATOMIC_RELAXED, __HIP_MEMORY_SCOPE_AGENT);
      if (cleanAll)
        hclean[(size_t)(tt * 256 + bi * 16 + b_) * HD + gi * 32 + hl_] = hv16;
      else if (tt == T - 1)
        hclean[(size_t)(bi * 16 + b_) * HD + gi * 32 + hl_] = hv16;
    }
    __syncthreads();   // drains every wave's vmcnt -> all data stores at the coherence point
    if (tid == 0)
      __hip_atomic_store(myflag, t + 1, __ATOMIC_RELAXED, __HIP_MEMORY_SCOPE_AGENT);
  }

  // save c state for next chunk
  cbuf[(size_t)(bi * 16 + b_) * HD + gi * 32 + hl_] = cv;
}

// ====================== final FC: y[b] = h_last[b,:] . fc_w + fc_b ======================
__global__ __launch_bounds__(64) void k_fc(const f16* __restrict__ hlast,
                                           const float* __restrict__ fcw,
                                           const float* __restrict__ fcb,
                                           float* __restrict__ out) {
  const int b = blockIdx.x, lane = threadIdx.x;
  const f16* hp = hlast + (size_t)b * HD + lane * 8;
  float s = 0.f;
#pragma unroll
  for (int j = 0; j < 8; j++) s += (float)hp[j] * fcw[lane * 8 + j];
  for (int off = 32; off; off >>= 1) s += __shfl_down(s, off);
  if (lane == 0) out[b] = s + fcb[0];
}

// ============================ host ============================
extern "C" void kernel_launch(void* const* d_in, const int* in_sizes, int n_in,
                              void* d_out, int out_size, void* d_ws, size_t ws_size,
                              hipStream_t stream) {
  (void)in_sizes; (void)n_in; (void)out_size;
  const float* x      = (const float*)d_in[0];
  const float* wih[3] = {(const float*)d_in[1], (const float*)d_in[4], (const float*)d_in[7]};
  const float* whh[3] = {(const float*)d_in[2], (const float*)d_in[5], (const float*)d_in[8]};
  const float* bia[3] = {(const float*)d_in[3], (const float*)d_in[6], (const float*)d_in[9]};
  const float* fcw = (const float*)d_in[10];
  const float* fcb = (const float*)d_in[11];
  float* out = (float*)d_out;

  char* ws = (char*)d_ws;
  size_t off = 0;
  auto alloc = [&](size_t bytes) -> char* {
    off = (off + 255) & ~(size_t)255;
    char* p = ws + off;
    off += bytes;
    return p;
  };

  // ---- fixed allocations ----
  f16* xin = (f16*)alloc((size_t)S_LEN * BATCH * NIN * 2);
  f16* wih16[3];
  wih16[0] = (f16*)alloc((size_t)G4 * NIN * 2);
  wih16[1] = (f16*)alloc((size_t)G4 * HD * 2);
  wih16[2] = (f16*)alloc((size_t)G4 * HD * 2);
  f16* whh16[3];
  for (int l = 0; l < 3; l++) whh16[l] = (f16*)alloc((size_t)G4 * HD * 2);
  float* cbuf[3];
  for (int l = 0; l < 3; l++) cbuf[l] = (float*)alloc((size_t)BATCH * HD * 4);
  f16* ring[3];
  for (int l = 0; l < 3; l++) ring[l] = (f16*)alloc((size_t)4 * BATCH * HD * 2);
  int* flags = (int*)alloc(3 * 256 * 4);
  f16* hclean2 = (f16*)alloc((size_t)BATCH * HD * 2);

  // ---- adaptive chunk length T ----
  int T = 64;
  while (T > 4) {
    size_t need = off + 8 * 256
                + 2 * ((size_t)T * BATCH * HD * 2 + 256)   // hclean0, hclean1
                + (size_t)T * BATCH * G4 * 2;              // xw
    if (need <= ws_size) break;
    T >>= 1;
  }
  f16* hclean01[2];
  hclean01[0] = (f16*)alloc((size_t)T * BATCH * HD * 2);
  hclean01[1] = (f16*)alloc((size_t)T * BATCH * HD * 2);
  f16* xw = (f16*)alloc((size_t)T * BATCH * G4 * 2);

  // ---- prep ----
  {
    int n = S_LEN * BATCH * NIN;
    k_x_transpose<<<dim3(n / 256), dim3(256), 0, stream>>>(x, xin);
  }
  k_f32_to_f16<<<dim3((G4 * NIN + 255) / 256), dim3(256), 0, stream>>>(wih[0], wih16[0], G4 * NIN);
  k_f32_to_f16<<<dim3((G4 * HD + 255) / 256), dim3(256), 0, stream>>>(wih[1], wih16[1], G4 * HD);
  k_f32_to_f16<<<dim3((G4 * HD + 255) / 256), dim3(256), 0, stream>>>(wih[2], wih16[2], G4 * HD);
  for (int l = 0; l < 3; l++)
    k_f32_to_f16<<<dim3((G4 * HD + 255) / 256), dim3(256), 0, stream>>>(whh[l], whh16[l], G4 * HD);
  // zero ring slot 0 (h_{-1}=0) of each layer + flags (end-of-kernel flush makes these MALL-visible)
  for (int l = 0; l < 3; l++)
    k_zero_i32<<<dim3(BATCH * HD / 2 / 256), dim3(256), 0, stream>>>((uint32_t*)ring[l],
                                                                     BATCH * HD / 2);
  k_zero_i32<<<dim3(3), dim3(256), 0, stream>>>((uint32_t*)flags, 3 * 256);

  // ---- chunk-interleaved layers ----
  for (int t0 = 0; t0 < S_LEN; t0 += T) {
    for (int l = 0; l < 3; l++) {
      dim3 pg(T * BATCH / 128, G4 / 128);
      if (l == 0) {
        const f16* Achunk = xin + (size_t)t0 * BATCH * NIN;
        k_proj<NIN><<<pg, dim3(256), 0, stream>>>(Achunk, wih16[0], bia[0], xw);
      } else {
        k_proj<HD><<<pg, dim3(256), 0, stream>>>(hclean01[l - 1], wih16[l], bia[l], xw);
      }
      f16* hc = (l == 2) ? hclean2 : hclean01[l];
      k_recur<<<dim3(256), dim3(512), 0, stream>>>(whh16[l], xw, ring[l], flags + l * 256,
                                                   hc, cbuf[l], t0, T, l != 2);
    }
  }

  // ---- final FC ----
  k_fc<<<dim3(BATCH), dim3(64), 0, stream>>>(hclean2, fcw, fcb, out);
}